// Round 13
// baseline (159.502 us; speedup 1.0000x reference)
//
#include <hip/hip_runtime.h>
#include <stdint.h>

// Otsu-variant threshold, 24 rows x 2^20 px, f32 in/out.
// f64-exact emulation of the np(float64) reference. R13 = R12 + icv/scan
// fused into the LAST k_hist block via ticket handshake with NO FENCES:
// flush atomics are device-scope (coherent-point), __syncthreads drains
// vmcnt before the ticket, last block reads tables with agent-scope atomic
// loads. (R6/R10/R11's 2x regression was the per-block __threadfence L2
// writeback storm, not the protocol.) Tail is LDS-staged (R11, ~40 VGPR).
// 3 dispatches: minmax(+zero), hist(+icv), out.

#define ROWS 24
#define NPIX (1 << 20)
#define NBINS 256
#define BPR 64                      // blocks per row
#define CHUNK (NPIX / BPR)          // 16384 elems per block
#define NBLK (ROWS * BPR)           // 1536
#define MAX_TRY 25                  // int(256*0.1)

typedef float f32x4 __attribute__((ext_vector_type(4)));
typedef unsigned long long u64;

static constexpr double kMagic = 6755399441055744.0;  // 1.5*2^52
static constexpr double Nd = 1048576.0;
static constexpr double kS19 = 524288.0;              // 2^19
static constexpr double kInv19 = 1.0 / 524288.0;      // 2^-19

// ws layout (bytes). part/t32 fully written each call; [OFF_CNT, ZERO_END)
// zeroed by k_minmax blocks 0..36 (covers cnt/cor/D1/D2/done).
#define OFF_PART  0                 // uint2[1536] per-block {min_bits,max_bits}
#define OFF_T32   12544             // float[24] final f32 thresholds
#define OFF_CNT   16384             // u32 [24][256] counts keyed by j
#define OFF_COR   40960             // i32 [24][256] floor-bin corrections
#define OFF_D1    65536             // u64 [24][256] sum q1 (delta*2^19/w RNE)
#define OFF_D2    114688            // u64 [24][256] sum q2 (delta^2*2^38/w^2)
#define OFF_DONE  163840            // u32 completion counter
#define ZERO_END  167936            // 37 * 4096

__device__ __forceinline__ unsigned ldg_u32(const unsigned* p) {
  return __hip_atomic_load(p, __ATOMIC_RELAXED, __HIP_MEMORY_SCOPE_AGENT);
}
__device__ __forceinline__ u64 ldg_u64(const u64* p) {
  return __hip_atomic_load(p, __ATOMIC_RELAXED, __HIP_MEMORY_SCOPE_AGENT);
}

// Reduce 1536 per-block partials to per-row min/max bits in LDS.
__device__ __forceinline__ void reduce_minmax(const uint2* __restrict__ part,
                                              unsigned* lmn, unsigned* lmx,
                                              int nthreads) {
  int t = threadIdx.x;
  if (t < ROWS) { lmn[t] = 0xFFFFFFFFu; lmx[t] = 0u; }
  __syncthreads();
  for (int p = t; p < NBLK; p += nthreads) {
    uint2 v = part[p];
    atomicMin(&lmn[p >> 6], v.x);   // x >= 0: uint bit order == float order
    atomicMax(&lmx[p >> 6], v.y);
  }
  __syncthreads();
}

// Call with ALL 64 lanes of wave 0 (t < 64): d defined (0) for lanes >= ROWS,
// so shfl sources are always initialized. gmax/256 valid in lane 0.
__device__ __forceinline__ double compute_w(const unsigned* lmn,
                                            const unsigned* lmx, int t) {
  double d = 0.0;
  if (t < ROWS)
    d = (double)__uint_as_float(lmx[t]) - (double)__uint_as_float(lmn[t]);
  for (int o = 16; o; o >>= 1) d = fmax(d, __shfl_down(d, o));
  return d / 256.0;  // exact pow2 scale
}

__global__ __launch_bounds__(256) void k_minmax(const float* __restrict__ x,
                                                uint2* __restrict__ part,
                                                uint4* __restrict__ zero_base) {
  int blk = blockIdx.x;
  if (blk < 37) {  // zero [OFF_CNT, ZERO_END): 37 * 4 KiB
    uint4 z; z.x = 0u; z.y = 0u; z.z = 0u; z.w = 0u;
    zero_base[blk * 256 + threadIdx.x] = z;
  }
  int row = blk / BPR, sub = blk % BPR;
  const float4* p = (const float4*)(x + (size_t)row * NPIX + (size_t)sub * CHUNK);
  float mn = 3.4e38f, mx = 0.0f;
  for (int i = threadIdx.x; i < CHUNK / 4; i += 256) {
    float4 v = p[i];
    mn = fminf(mn, fminf(fminf(v.x, v.y), fminf(v.z, v.w)));
    mx = fmaxf(mx, fmaxf(fmaxf(v.x, v.y), fmaxf(v.z, v.w)));
  }
  __shared__ float smn[4], smx[4];
  for (int o = 32; o; o >>= 1) {   // all 64 lanes active here
    mn = fminf(mn, __shfl_down(mn, o));
    mx = fmaxf(mx, __shfl_down(mx, o));
  }
  int wave = threadIdx.x >> 6;
  if ((threadIdx.x & 63) == 0) { smn[wave] = mn; smx[wave] = mx; }
  __syncthreads();
  if (threadIdx.x == 0) {
    for (int w = 1; w < 4; ++w) { mn = fminf(mn, smn[w]); mx = fmaxf(mx, smx[w]); }
    uint2 r; r.x = __float_as_uint(mn); r.y = __float_as_uint(mx);
    part[blk] = r;
  }
}

__global__ __launch_bounds__(256) void k_hist(const float* __restrict__ x,
    const uint2* __restrict__ part,
    unsigned* __restrict__ gcnt, int* __restrict__ gcor,
    u64* __restrict__ gD1, u64* __restrict__ gD2,
    unsigned* __restrict__ gdone, float* __restrict__ t32g) {
  // Aliased LDS pool (13312 B).
  // Hist:  hA u64[4][256] @0 | h2 u32[4][256] @8192 | hcor i32[256] @12288
  // Tail:  2 wave-slots of 6144 B: E1 f64[256] | E2 f64[256] | CC u64[256]
  __shared__ __align__(16) char pool[13312];
  __shared__ unsigned lmn[ROWS], lmx[ROWS];
  __shared__ double s_w, s_rmin;
  __shared__ u64 umask[ROWS][4];
  __shared__ u64 ganyw[4];
  __shared__ unsigned s_last;
  __shared__ int s_tstop;
  u64* hA = (u64*)pool;                  // packed (cnt<<32 | q1sum) per wave
  unsigned* h2 = (unsigned*)(pool + 8192);
  int* hcor = (int*)(pool + 12288);
  int t = threadIdx.x;
  int row = blockIdx.x / BPR, sub = blockIdx.x % BPR;
  int wavei = t >> 6, lane = t & 63;
#pragma unroll
  for (int wv = 0; wv < 4; ++wv) { hA[wv * NBINS + t] = 0ull; h2[wv * NBINS + t] = 0u; }
  hcor[t] = 0;
  reduce_minmax(part, lmn, lmx, 256);
  if (t < 64) {
    double wv = compute_w(lmn, lmx, t);
    if (t == 0) { s_w = wv; s_rmin = (double)__uint_as_float(lmn[row]); }
  }
  __syncthreads();
  double w = s_w, rmin = s_rmin, rw = 1.0 / w;
  double rs1 = kS19 / w;            // quantizer: q1 = RNE(delta * 2^19/w)
  double rs2 = rs1 * rs1 * kInv19;  // q2 = RNE(delta^2 * 2^38/w^2), <= 2^19
  double lo_eps = w * 1e-9, hi_eps = w * (1.0 - 1e-9);
  const float4* p = (const float4*)(x + (size_t)row * NPIX + (size_t)sub * CHUNK);
  for (int i = t; i < CHUNK / 4; i += 256) {
    float4 v = p[i];
    float vv[4] = {v.x, v.y, v.z, v.w};
#pragma unroll
    for (int c = 0; c < 4; ++c) {
      double xs = (double)vv[c] - rmin;       // exact in f64
      double q1 = xs * rw;                    // ~1ulp of xs/w
      int b = (int)q1;                        // q1 >= 0
      double delta = fma(-(double)b, w, xs);  // xs - b*w, single rounding
      int j = b;
      if (__builtin_expect(!(delta >= lo_eps) | !(delta <= hi_eps) | (b > 255), 0)) {
        // near a bin boundary (margin 1e-9*w >> all rounding error) or top bin:
        // exact reference semantics with f64 division + Sterbenz-exact delta.
        double q = xs / w;
        b = (int)q; if (b > 255) b = 255;
        double elo = (double)b * w, ehi = (double)(b + 1) * w;
        j = b; double off = elo;
        if (xs > ehi) { if (b < 255) { j = b + 1; off = ehi; } }
        else if (b > 0 && xs <= elo) { j = b - 1; off = (double)j * w; }
        if (j != b) { atomicAdd(&hcor[b], 1); atomicAdd(&hcor[j], -1); }
        delta = xs - off;                     // exact (Sterbenz)
      }
      // RNE quantize via magic constant; values < 2^20 so low-32 cast exact
      double t1 = fma(delta, rs1, kMagic);
      double t2 = fma(delta * delta, rs2, kMagic);
      unsigned q1i = (unsigned)__double_as_longlong(t1);
      unsigned q2i = (unsigned)__double_as_longlong(t2);
      // packed: cnt in bits 32+; per-wave q1sum <= 4096*2^19 = 2^31, no carry
      atomicAdd(&hA[wavei * NBINS + j], (1ull << 32) | (u64)q1i);
      atomicAdd(&h2[wavei * NBINS + j], q2i);
    }
  }
  __syncthreads();
  // merge wave-private hists (unpack BEFORE summing: 4x q1sum could carry);
  // flush via DEVICE-SCOPE atomics (performed at coherent point)
  unsigned c = 0; u64 a = 0;
#pragma unroll
  for (int wv = 0; wv < 4; ++wv) {
    u64 pk = hA[wv * NBINS + t];
    c += (unsigned)(pk >> 32);
    a += pk & 0xffffffffull;
  }
  u64 b2 = (u64)h2[t] + h2[NBINS + t] + h2[2 * NBINS + t] + h2[3 * NBINS + t];
  int base = row * NBINS + t;
  if (c) {
    atomicAdd(&gcnt[base], c);
    if (a) atomicAdd(&gD1[base], a);
    if (b2) atomicAdd(&gD2[base], b2);
  }
  if (hcor[t]) atomicAdd(&gcor[base], hcor[t]);

  // ---- ticket: NO fences. __syncthreads drains vmcnt(0), so the flush
  // atomics above are acked at the coherent point before the ticket issues.
  __syncthreads();
  if (t == 0) s_last = (atomicAdd(gdone, 1u) == NBLK - 1) ? 1u : 0u;
  __syncthreads();
  if (!s_last) return;

  // ---- tail (last block only): icv + early-stop scan, LDS-staged.
  // 2 active waves x 12 rows; reads tables via agent-scope atomic loads.
  if (t < 4) ganyw[t] = 0ull;
  __syncthreads();
  const double dNAN = __builtin_nan("");
  double wv2 = s_w;
  double is1 = wv2 * kInv19;             // q1 -> delta units: w*2^-19
  double is2 = is1 * is1 * kS19;         // q2 -> delta^2 units: w^2*2^-38
  if (wavei < 2) {
    double* E1 = (double*)(pool + wavei * 6144);
    double* E2 = (double*)(pool + wavei * 6144 + 2048);
    u64* CCp = (u64*)(pool + wavei * 6144 + 4096);
    for (int pass = 0; pass < 12; ++pass) {
      int r = wavei * 12 + pass;
      // phase 1: inclusive prefix sums over 256 bins (4 wave scans w/ carry)
      double c1 = 0.0, c2 = 0.0;
      u64 cc = 0ull;
      for (int k = 0; k < 4; ++k) {
        int bin = k * 64 + lane;
        int idx = r * NBINS + bin;
        unsigned n = ldg_u32(&gcnt[idx]);
        int cor = (int)ldg_u32((const unsigned*)&gcor[idx]);
        double d1 = (double)ldg_u64(&gD1[idx]) * is1;    // sum(delta)
        double d2v = (double)ldg_u64(&gD2[idx]) * is2;   // sum(delta^2)
        double elo = (double)bin * wv2;
        double p1 = (double)n * elo + d1;                          // sum(xs)
        double p2 = (double)n * (elo * elo) + 2.0 * elo * d1 + d2v;  // xs^2
        u64 pc = (u64)n | ((u64)(unsigned)(n + (unsigned)cor) << 32);
        for (int o = 1; o < 64; o <<= 1) {
          double u1 = __shfl_up(p1, o), u2 = __shfl_up(p2, o);
          u64 uc = __shfl_up(pc, o);
          if (lane >= o) { p1 += u1; p2 += u2; pc += uc; }
        }
        E1[bin] = p1 + c1; E2[bin] = p2 + c2; CCp[bin] = pc + cc;
        c1 += __shfl(p1, 63); c2 += __shfl(p2, 63); cc += __shfl(pc, 63);
      }
      double mean = c1 / Nd;
      double tot1 = c1 - Nd * mean;
      double tot2 = c2 - Nd * mean * mean;
      // phase 2: icv per bin + update-bit masks (reference argmax semantics)
      double m = 0.0;
      for (int k = 0; k < 4; ++k) {
        int bin = k * 64 + lane;
        double s1v = E1[bin], s2v = E2[bin];
        u64 ccv = CCp[bin];
        unsigned n0i = (unsigned)(ccv & 0xffffffffull);
        double n0 = (double)n0i;
        double n1 = Nd - n0;
        double S1 = s1v - n0 * mean;
        double S2 = s2v - 2.0 * mean * s1v + n0 * mean * mean;
        double mu0 = (n0i > 1u) ? (S2 - S1 * S1 / n0) / (n0 - 1.0) : dNAN;
        double S1b = tot1 - S1, S2b = tot2 - S2;
        double mu1 = (n1 > 1.0) ? (S2b - S1b * S1b / n1) / (n1 - 1.0) : dNAN;
        double w0 = (double)(unsigned)(ccv >> 32) / Nd, w1v = 1.0 - w0;
        double ddv = mu0 - mu1;
        double v = w0 * w1v * ddv * ddv;  // NaN propagates (n<=1 cases)
        // U[bin] = icv[bin] > max(0, nanmax(icv[0..bin-1]))
        double pm = v;                    // inclusive prefix-max (fmax drops NaN)
        for (int o = 1; o < 64; o <<= 1) {
          double u = __shfl_up(pm, o);
          if (lane >= o) pm = fmax(pm, u);
        }
        double excl = __shfl_up(pm, 1);
        double Mprev = (lane == 0) ? m : fmax(m, excl);
        bool upd = v > Mprev;             // NaN v -> false, like reference
        u64 msk = __ballot(upd);
        if (lane == 0) { umask[r][k] = msk; atomicOr(&ganyw[k], msk); }
        m = fmax(m, __shfl(pm, 63));
      }
    }
  }
  __syncthreads();
  if (t == 0) {
    // reference scan: stop after MAX_TRY consecutive bins with no update in
    // ANY row => updates allowed for bins <= tstop.
    int no_upd = 0, tstop = 255;
    for (int b = 0; b < 256; ++b) {
      bool any = (ganyw[b >> 6] >> (b & 63)) & 1ull;
      if (any) no_upd = 0; else ++no_upd;
      if (no_upd >= MAX_TRY) { tstop = b; break; }
    }
    s_tstop = tstop;
  }
  __syncthreads();
  if (t < ROWS) {
    int tstop = s_tstop;
    int tbest = -1;
    for (int k = 3; k >= 0; --k) {
      u64 msk = umask[t][k];
      int hi = k * 64 + 63;
      if (hi > tstop) {
        int shift = tstop - k * 64;
        if (shift < 0) msk = 0ull;
        else msk &= (shift >= 63) ? ~0ull : ((2ull << shift) - 1ull);
      }
      if (msk) { tbest = k * 64 + 63 - __clzll(msk); break; }
    }
    double rmin = (double)__uint_as_float(lmn[t]);
    double ft = (tbest >= 0) ? (double)(tbest + 1) * wv2 + rmin : rmin;
    // t32 = smallest f32 >= ft (then f32 x < t32  <=>  (f64)x < ft)
    float f = (float)ft;
    if ((double)f < ft) f = __uint_as_float(__float_as_uint(f) + 1u);
    t32g[t] = f;
  }
}

__global__ __launch_bounds__(256) void k_out(const float* __restrict__ x,
                                             const float* __restrict__ t32g,
                                             float* __restrict__ out) {
  size_t i = (size_t)blockIdx.x * blockDim.x + threadIdx.x;
  size_t stride = (size_t)gridDim.x * blockDim.x;
  const f32x4* xin = (const f32x4*)x;
  f32x4* o = (f32x4*)out;
  size_t n4 = (size_t)ROWS * NPIX / 4;
  for (; i < n4; i += stride) {
    float ft = t32g[i >> 18];  // 2^18 float4 per row
    f32x4 v = xin[i];
    f32x4 rr;
    rr.x = (v.x < ft) ? 0.0f : v.x;
    rr.y = (v.y < ft) ? 0.0f : v.y;
    rr.z = (v.z < ft) ? 0.0f : v.z;
    rr.w = (v.w < ft) ? 0.0f : v.w;
    o[i] = rr;  // plain store: absorb into L3, flush overlaps next phase
  }
}

extern "C" void kernel_launch(void* const* d_in, const int* in_sizes, int n_in,
                              void* d_out, int out_size, void* d_ws, size_t ws_size,
                              hipStream_t stream) {
  const float* x = (const float*)d_in[0];
  float* out = (float*)d_out;
  char* ws = (char*)d_ws;
  uint2* part = (uint2*)(ws + OFF_PART);
  float* t32g = (float*)(ws + OFF_T32);
  unsigned* gcnt = (unsigned*)(ws + OFF_CNT);
  int* gcor = (int*)(ws + OFF_COR);
  u64* gD1 = (u64*)(ws + OFF_D1);
  u64* gD2 = (u64*)(ws + OFF_D2);
  unsigned* gdone = (unsigned*)(ws + OFF_DONE);

  k_minmax<<<NBLK, 256, 0, stream>>>(x, part, (uint4*)(ws + OFF_CNT));
  k_hist<<<NBLK, 256, 0, stream>>>(x, part, gcnt, gcor, gD1, gD2, gdone, t32g);
  k_out<<<3072, 256, 0, stream>>>(x, t32g, out);
}

// Round 14
// 113.395 us; speedup vs baseline: 1.4066x; 1.4066x over previous
//
#include <hip/hip_runtime.h>
#include <stdint.h>

// Otsu-variant threshold, 24 rows x 2^20 px, f32 in/out.
// f64-exact emulation of the np(float64) reference. R14 = R12 (best: 115us,
// 4 dispatches, fence-free -- all fusion variants regressed: fences cost
// ~90us L2-storm, fused tails cost ~50us serial whole-GPU-idle) + 2x manual
// unroll with dual prefetch in k_hist (latency-bound per R13 counters:
// VALUBusy 10.5%, BW 0.5TB/s -> double per-thread ILP).

#define ROWS 24
#define NPIX (1 << 20)
#define NBINS 256
#define BPR 64                      // blocks per row
#define CHUNK (NPIX / BPR)          // 16384 elems per block
#define NBLK (ROWS * BPR)           // 1536
#define MAX_TRY 25                  // int(256*0.1)

typedef float f32x4 __attribute__((ext_vector_type(4)));
typedef unsigned long long u64;

static constexpr double kMagic = 6755399441055744.0;  // 1.5*2^52
static constexpr double Nd = 1048576.0;
static constexpr double kS19 = 524288.0;              // 2^19
static constexpr double kInv19 = 1.0 / 524288.0;      // 2^-19

// ws layout (bytes). part/t32 fully written each call; [OFF_CNT, ZERO_END)
// zeroed by k_minmax blocks 0..35.
#define OFF_PART  0                 // uint2[1536] per-block {min_bits,max_bits}
#define OFF_FINAL 12288             // double[24]
#define OFF_T32   12544             // float[24] final f32 thresholds
#define OFF_CNT   16384             // u32 [24][256] counts keyed by j
#define OFF_COR   40960             // i32 [24][256] floor-bin corrections
#define OFF_D1    65536             // u64 [24][256] sum q1 (delta*2^19/w RNE)
#define OFF_D2    114688            // u64 [24][256] sum q2 (delta^2*2^38/w^2)
#define ZERO_END  163840

// Reduce 1536 per-block partials to per-row min/max bits in LDS.
__device__ __forceinline__ void reduce_minmax(const uint2* __restrict__ part,
                                              unsigned* lmn, unsigned* lmx,
                                              int nthreads) {
  int t = threadIdx.x;
  if (t < ROWS) { lmn[t] = 0xFFFFFFFFu; lmx[t] = 0u; }
  __syncthreads();
  for (int p = t; p < NBLK; p += nthreads) {
    uint2 v = part[p];
    atomicMin(&lmn[p >> 6], v.x);   // x >= 0: uint bit order == float order
    atomicMax(&lmx[p >> 6], v.y);
  }
  __syncthreads();
}

// Call with ALL 64 lanes of wave 0 (t < 64): d defined (0) for lanes >= ROWS,
// so shfl sources are always initialized. gmax/256 valid in lane 0.
__device__ __forceinline__ double compute_w(const unsigned* lmn,
                                            const unsigned* lmx, int t) {
  double d = 0.0;
  if (t < ROWS)
    d = (double)__uint_as_float(lmx[t]) - (double)__uint_as_float(lmn[t]);
  for (int o = 16; o; o >>= 1) d = fmax(d, __shfl_down(d, o));
  return d / 256.0;  // exact pow2 scale
}

__global__ __launch_bounds__(256) void k_minmax(const float* __restrict__ x,
                                                uint2* __restrict__ part,
                                                uint4* __restrict__ zero_base) {
  int blk = blockIdx.x;
  if (blk < 36) {  // zero [OFF_CNT, ZERO_END): 36 * 4 KiB
    uint4 z; z.x = 0u; z.y = 0u; z.z = 0u; z.w = 0u;
    zero_base[blk * 256 + threadIdx.x] = z;
  }
  int row = blk / BPR, sub = blk % BPR;
  const float4* p = (const float4*)(x + (size_t)row * NPIX + (size_t)sub * CHUNK);
  float mn = 3.4e38f, mx = 0.0f;
  for (int i = threadIdx.x; i < CHUNK / 4; i += 256) {
    float4 v = p[i];
    mn = fminf(mn, fminf(fminf(v.x, v.y), fminf(v.z, v.w)));
    mx = fmaxf(mx, fmaxf(fmaxf(v.x, v.y), fmaxf(v.z, v.w)));
  }
  __shared__ float smn[4], smx[4];
  for (int o = 32; o; o >>= 1) {   // all 64 lanes active here
    mn = fminf(mn, __shfl_down(mn, o));
    mx = fmaxf(mx, __shfl_down(mx, o));
  }
  int wave = threadIdx.x >> 6;
  if ((threadIdx.x & 63) == 0) { smn[wave] = mn; smx[wave] = mx; }
  __syncthreads();
  if (threadIdx.x == 0) {
    for (int w = 1; w < 4; ++w) { mn = fminf(mn, smn[w]); mx = fmaxf(mx, smx[w]); }
    uint2 r; r.x = __float_as_uint(mn); r.y = __float_as_uint(mx);
    part[blk] = r;
  }
}

__global__ __launch_bounds__(256) void k_hist(const float* __restrict__ x,
    const uint2* __restrict__ part,
    unsigned* __restrict__ gcnt, int* __restrict__ gcor,
    u64* __restrict__ gD1, u64* __restrict__ gD2) {
  __shared__ unsigned lmn[ROWS], lmx[ROWS];
  __shared__ u64 hA[4][NBINS];       // per-wave packed (cnt<<32 | q1sum)
  __shared__ unsigned h2[4][NBINS];  // per-wave q2 sums
  __shared__ int hcor[NBINS];
  __shared__ double s_w, s_rmin;
  int t = threadIdx.x;
  int row = blockIdx.x / BPR, sub = blockIdx.x % BPR;
  int wavei = t >> 6;
#pragma unroll
  for (int wv = 0; wv < 4; ++wv) { hA[wv][t] = 0ull; h2[wv][t] = 0u; }
  hcor[t] = 0;
  reduce_minmax(part, lmn, lmx, 256);
  if (t < 64) {
    double wv = compute_w(lmn, lmx, t);
    if (t == 0) { s_w = wv; s_rmin = (double)__uint_as_float(lmn[row]); }
  }
  __syncthreads();
  double w = s_w, rmin = s_rmin, rw = 1.0 / w;
  double rs1 = kS19 / w;            // quantizer: q1 = RNE(delta * 2^19/w)
  double rs2 = rs1 * rs1 * kInv19;  // q2 = RNE(delta^2 * 2^38/w^2), <= 2^19
  double lo_eps = w * 1e-9, hi_eps = w * (1.0 - 1e-9);
  const float4* p = (const float4*)(x + (size_t)row * NPIX + (size_t)sub * CHUNK);

  // per-element pipeline body (bit-identical math to R12)
  auto process = [&](float fv) {
    double xs = (double)fv - rmin;          // exact in f64
    double q1 = xs * rw;                    // ~1ulp of xs/w
    int b = (int)q1;                        // q1 >= 0
    double delta = fma(-(double)b, w, xs);  // xs - b*w, single rounding
    int j = b;
    if (__builtin_expect(!(delta >= lo_eps) | !(delta <= hi_eps) | (b > 255), 0)) {
      // near a bin boundary (margin 1e-9*w >> all rounding error) or top bin:
      // exact reference semantics with f64 division + Sterbenz-exact delta.
      double q = xs / w;
      b = (int)q; if (b > 255) b = 255;
      double elo = (double)b * w, ehi = (double)(b + 1) * w;
      j = b; double off = elo;
      if (xs > ehi) { if (b < 255) { j = b + 1; off = ehi; } }
      else if (b > 0 && xs <= elo) { j = b - 1; off = (double)j * w; }
      if (j != b) { atomicAdd(&hcor[b], 1); atomicAdd(&hcor[j], -1); }
      delta = xs - off;                     // exact (Sterbenz)
    }
    // RNE quantize via magic constant; values < 2^20 so low-32 cast exact
    double t1 = fma(delta, rs1, kMagic);
    double t2 = fma(delta * delta, rs2, kMagic);
    unsigned q1i = (unsigned)__double_as_longlong(t1);
    unsigned q2i = (unsigned)__double_as_longlong(t2);
    // packed: cnt in bits 32+; per-wave q1sum <= 4096*2^19 = 2^31, no carry
    atomicAdd(&hA[wavei][j], (1ull << 32) | (u64)q1i);
    atomicAdd(&h2[wavei][j], q2i);
  };

  // 2x unroll, dual prefetch: CHUNK/4 = 4096, stride 256 -> exactly 16 iters
  // -> 8 double-iters, no remainder. Two independent f64 chains in flight.
  for (int i = t; i < CHUNK / 4; i += 512) {
    float4 v0 = p[i];
    float4 v1 = p[i + 256];
    process(v0.x); process(v1.x);
    process(v0.y); process(v1.y);
    process(v0.z); process(v1.z);
    process(v0.w); process(v1.w);
  }
  __syncthreads();
  // merge wave-private hists (unpack BEFORE summing: 4x q1sum could carry)
  unsigned c = 0; u64 a = 0;
#pragma unroll
  for (int wv = 0; wv < 4; ++wv) {
    u64 pk = hA[wv][t];
    c += (unsigned)(pk >> 32);
    a += pk & 0xffffffffull;
  }
  u64 b2 = (u64)h2[0][t] + h2[1][t] + h2[2][t] + h2[3][t];
  int base = row * NBINS + t;
  if (c) {
    atomicAdd(&gcnt[base], c);
    if (a) atomicAdd(&gD1[base], a);
    if (b2) atomicAdd(&gD2[base], b2);
  }
  if (hcor[t]) atomicAdd(&gcor[base], hcor[t]);
}

// One block, 1024 threads: icv for all 24 rows (wave-parallel prefix sums),
// mask-based early-stop scan, final thresholds (f64 + rounded-up f32).
__global__ __launch_bounds__(1024) void k_icv_scan(
    const unsigned* __restrict__ gcnt, const int* __restrict__ gcor,
    const u64* __restrict__ gD1, const u64* __restrict__ gD2,
    const uint2* __restrict__ part,
    double* __restrict__ finalt, float* __restrict__ t32g) {
  __shared__ unsigned lmn[ROWS], lmx[ROWS];
  __shared__ u64 umask[ROWS][4];
  __shared__ u64 ganyw[4];
  __shared__ double s_w;
  __shared__ int s_tstop;
  int t = threadIdx.x;
  if (t < 4) ganyw[t] = 0ull;
  if (t < ROWS * 4) ((u64*)umask)[t] = 0ull;
  reduce_minmax(part, lmn, lmx, 1024);
  if (t < 64) {
    double wv = compute_w(lmn, lmx, t);
    if (t == 0) s_w = wv;
  }
  __syncthreads();
  double w = s_w;
  double is1 = w * kInv19;          // q1 -> delta units: w*2^-19
  double is2 = is1 * is1 * kS19;    // q2 -> delta^2 units: w^2*2^-38
  int wave = t >> 6, lane = t & 63;
  const double dNAN = __builtin_nan("");

  for (int pass = 0; pass < 2; ++pass) {
    if (pass == 1 && wave >= 8) break;   // no __syncthreads inside this loop
    int r = pass ? 16 + wave : wave;
    // lane handles bins {lane, 64+lane, 128+lane, 192+lane}
    double e1[4], e2[4];
    u64 pc0[4];
#pragma unroll
    for (int k = 0; k < 4; ++k) {
      int bin = k * 64 + lane;
      int idx = r * NBINS + bin;
      unsigned n = gcnt[idx];
      int cor = gcor[idx];
      double d1 = (double)gD1[idx] * is1;    // sum(delta) in bin
      double d2v = (double)gD2[idx] * is2;   // sum(delta^2) in bin
      double elo = (double)bin * w;
      e1[k] = (double)n * elo + d1;                            // sum(xs)
      e2[k] = (double)n * (elo * elo) + 2.0 * elo * d1 + d2v;  // sum(xs^2)
      pc0[k] = (u64)n | ((u64)(unsigned)(n + (unsigned)cor) << 32);
    }
    // inclusive prefix sums over bins: 4 wave scans with carry
    double c1 = 0.0, c2 = 0.0;
    u64 cc = 0ull;
    double E1[4], E2[4];
    u64 CC[4];
#pragma unroll
    for (int k = 0; k < 4; ++k) {
      double p1 = e1[k], p2 = e2[k];
      u64 pc = pc0[k];
      for (int o = 1; o < 64; o <<= 1) {
        double u1 = __shfl_up(p1, o), u2 = __shfl_up(p2, o);
        u64 uc = __shfl_up(pc, o);
        if (lane >= o) { p1 += u1; p2 += u2; pc += uc; }
      }
      E1[k] = p1 + c1; E2[k] = p2 + c2; CC[k] = pc + cc;
      c1 += __shfl(p1, 63); c2 += __shfl(p2, 63); cc += __shfl(pc, 63);
    }
    double mean = c1 / Nd;
    double tot1 = c1 - Nd * mean;
    double tot2 = c2 - Nd * mean * mean;
    double icv4[4];
#pragma unroll
    for (int k = 0; k < 4; ++k) {
      unsigned n0i = (unsigned)(CC[k] & 0xffffffffull);
      double n0 = (double)n0i;
      double n1 = Nd - n0;
      double S1 = E1[k] - n0 * mean;
      double S2 = E2[k] - 2.0 * mean * E1[k] + n0 * mean * mean;
      double mu0 = (n0i > 1u) ? (S2 - S1 * S1 / n0) / (n0 - 1.0) : dNAN;
      double S1b = tot1 - S1, S2b = tot2 - S2;
      double mu1 = (n1 > 1.0) ? (S2b - S1b * S1b / n1) / (n1 - 1.0) : dNAN;
      double w0 = (double)(unsigned)(CC[k] >> 32) / Nd, w1v = 1.0 - w0;
      double ddv = mu0 - mu1;
      icv4[k] = w0 * w1v * ddv * ddv;   // NaN propagates (n<=1 cases)
    }
    // update bits: U[b] = icv[b] > max(0, nanmax(icv[0..b-1]))
    double m = 0.0;
    u64 myMask[4];
#pragma unroll
    for (int k = 0; k < 4; ++k) {
      double v = icv4[k];
      double pm = v;  // inclusive prefix-max (fmax drops NaN)
      for (int o = 1; o < 64; o <<= 1) {
        double u = __shfl_up(pm, o);
        if (lane >= o) pm = fmax(pm, u);
      }
      double excl = __shfl_up(pm, 1);
      double Mprev = (lane == 0) ? m : fmax(m, excl);
      bool upd = v > Mprev;             // NaN v -> false, like reference
      myMask[k] = __ballot(upd);
      m = fmax(m, __shfl(pm, 63));
    }
    if (lane == 0) {
#pragma unroll
      for (int k = 0; k < 4; ++k) {
        umask[r][k] = myMask[k];
        atomicOr(&ganyw[k], myMask[k]);
      }
    }
  }
  __syncthreads();
  if (t == 0) {
    // reference scan: stop after MAX_TRY consecutive bins with no update in
    // ANY row => updates allowed for bins <= tstop.
    int no_upd = 0, tstop = 255;
    for (int b = 0; b < 256; ++b) {
      bool any = (ganyw[b >> 6] >> (b & 63)) & 1ull;
      if (any) no_upd = 0; else ++no_upd;
      if (no_upd >= MAX_TRY) { tstop = b; break; }
    }
    s_tstop = tstop;
  }
  __syncthreads();
  if (t < ROWS) {
    int tstop = s_tstop;
    int tbest = -1;
    for (int k = 3; k >= 0; --k) {
      u64 msk = umask[t][k];
      int hi = k * 64 + 63;
      if (hi > tstop) {
        int shift = tstop - k * 64;
        if (shift < 0) msk = 0ull;
        else msk &= (shift >= 63) ? ~0ull : ((2ull << shift) - 1ull);
      }
      if (msk) { tbest = k * 64 + 63 - __clzll(msk); break; }
    }
    double rmin = (double)__uint_as_float(lmn[t]);
    double ft = (tbest >= 0) ? (double)(tbest + 1) * w + rmin : rmin;
    finalt[t] = ft;
    // t32 = smallest f32 >= ft (then f32 x < t32  <=>  (f64)x < ft)
    float f = (float)ft;
    if ((double)f < ft) f = __uint_as_float(__float_as_uint(f) + 1u);
    t32g[t] = f;
  }
}

__global__ __launch_bounds__(256) void k_out(const float* __restrict__ x,
                                             const float* __restrict__ t32g,
                                             float* __restrict__ out) {
  size_t i = (size_t)blockIdx.x * blockDim.x + threadIdx.x;
  size_t stride = (size_t)gridDim.x * blockDim.x;
  const f32x4* xin = (const f32x4*)x;
  f32x4* o = (f32x4*)out;
  size_t n4 = (size_t)ROWS * NPIX / 4;
  for (; i < n4; i += stride) {
    float ft = t32g[i >> 18];  // 2^18 float4 per row
    f32x4 v = xin[i];
    f32x4 rr;
    rr.x = (v.x < ft) ? 0.0f : v.x;
    rr.y = (v.y < ft) ? 0.0f : v.y;
    rr.z = (v.z < ft) ? 0.0f : v.z;
    rr.w = (v.w < ft) ? 0.0f : v.w;
    o[i] = rr;  // plain store: absorb into L3, flush overlaps next phase
  }
}

extern "C" void kernel_launch(void* const* d_in, const int* in_sizes, int n_in,
                              void* d_out, int out_size, void* d_ws, size_t ws_size,
                              hipStream_t stream) {
  const float* x = (const float*)d_in[0];
  float* out = (float*)d_out;
  char* ws = (char*)d_ws;
  uint2* part = (uint2*)(ws + OFF_PART);
  double* finalt = (double*)(ws + OFF_FINAL);
  float* t32g = (float*)(ws + OFF_T32);
  unsigned* gcnt = (unsigned*)(ws + OFF_CNT);
  int* gcor = (int*)(ws + OFF_COR);
  u64* gD1 = (u64*)(ws + OFF_D1);
  u64* gD2 = (u64*)(ws + OFF_D2);

  k_minmax<<<NBLK, 256, 0, stream>>>(x, part, (uint4*)(ws + OFF_CNT));
  k_hist<<<NBLK, 256, 0, stream>>>(x, part, gcnt, gcor, gD1, gD2);
  k_icv_scan<<<1, 1024, 0, stream>>>(gcnt, gcor, gD1, gD2, part, finalt, t32g);
  k_out<<<3072, 256, 0, stream>>>(x, t32g, out);
}